// Round 6
// baseline (130.241 us; speedup 1.0000x reference)
//
#include <hip/hip_runtime.h>
#include <hip/hip_fp16.h>

#define HH 128
#define NB 4
#define NVOX (NB * HH * HH * HH)   // 8,388,608 = 2^23 voxels per image

// pass1 v11: v10 math with 1-wave blocks (64 thr, 8192 blocks) + XCD-chunked
// block swizzle. No barriers, no LDS in pass1; each wave schedules/retires
// independently (attacks the 30% OccupancyPercent / 51% VALUBusy stall), and
// each XCD owns one (img,b) slab so all halo re-reads are same-XCD L2 hits.
// Keeps: per-lane overlapping float4 d-window, depth-1 row prefetch, raw
// v_sqrt, pair-square epilogue, pre-sqrt min/max tracking.
#define NBLK1 8192                 // img2 * b4 * hstrip16 * colpair64
#define GRID2 512
#define TPB 256

typedef float vf2 __attribute__((ext_vector_type(2)));
typedef float vf4 __attribute__((ext_vector_type(4)));
typedef vf4 vf4u __attribute__((aligned(4)));   // 4B-aligned float4 load type

// Slot arrays: every slot written by pass1 every call before pass2 reads them
// (dispatch-boundary ordering). No init kernel, no atomics on these.
__device__ __align__(16) unsigned int g_bmin[NBLK1];
__device__ __align__(16) unsigned int g_bmax[NBLK1];

union U4H8 { uint4 u; __half2 h[4]; };

// ---------------------------------------------------------------------------
// Pass 1 (register-only, packed fp32, 2 cols/wave, no LDS, no barrier).
// Ops per axis: s=(1,2,1), d=(-1,0,1), u=(1,1,1).
//   Sx=Gssd Sy=Gsds Sz=Gdss ; Sd11=Gsud-Gsdu Sd12=Gsud+Gsdu
//   Sd21=Gdus-Guds Sd22=Gdus+Guds ; Sd31=Gusd-Gdsu Sd32=Gusd+Gdsu
// Pair identity: (A-B)^2+(A+B)^2 = 2A^2+2B^2, so only 9 G-quantities matter:
//   s = 9e-6 + Gssd^2+Gsds^2+Gdss^2 + 2[Gsud^2+Gsdu^2+Gdus^2+Guds^2+Gusd^2+Gdsu^2]
// Reflect pad=1: -1 -> 1, 128 -> 126. h,w wave-uniform; d per-lane window.
// ---------------------------------------------------------------------------
__global__ __launch_bounds__(64) void pass1_kernel(
    const float* __restrict__ x, const float* __restrict__ y,
    __half* __restrict__ magx, __half* __restrict__ magy,
    float* __restrict__ out) {
    int bid = blockIdx.x;
    int lane = threadIdx.x;            // 64-thread block = one wave
    if (bid == 0 && lane == 0) out[0] = 0.0f;   // poison-clear for pass2 atomics

    // XCD-chunked bijective swizzle (8192 % 8 == 0): each XCD gets 1024
    // consecutive wgids = exactly one (img,b) slab -> halo reuse in-XCD.
    int wgid = (bid & 7) * 1024 + (bid >> 3);

    int cp  = wgid & 63;               // column pair: w = {2cp, 2cp+1}
    int hs  = (wgid >> 6) & 15;
    int b   = (wgid >> 10) & 3;
    int img = wgid >> 12;

    const float* __restrict__ src = img ? y : x;
    __half* __restrict__ dst = img ? magy : magx;

    int w0 = cp * 2;                   // first output column (even)
    int w1 = w0 + 1;                   // second output column
    int cw0 = (w0 == 0) ? 1 : (w0 - 1);
    int cw3 = (w1 == 127) ? 126 : (w1 + 1);
    int h0 = hs << 3;                  // 8 output rows per block
    const float* __restrict__ srcb = src + ((size_t)b << 21);

    // per-lane d-window start: floats {fo..fo+3}; interior fo = 2*lane-1
    int fo = 2 * lane - 1;
    fo = (fo < 0) ? 0 : ((fo > 124) ? 124 : fo);

    const vf2 two = {2.0f, 2.0f};

    // ring state per output column: 7 vf2 quantities x 3 slots
    vf2 sbD[2][3], ubD[2][3], dbS[2][3], sbS[2][3], ubS[2][3], dbU[2][3], sbU[2][3];
    vf2 smn = {3.4e38f, 3.4e38f};      // min/max tracked on s (pre-sqrt)
    vf2 smx = {0.0f, 0.0f};
    bool l0 = (lane == 0), l63 = (lane == 63), le = l0 || l63;

    auto loadrow = [&](int r, vf4* q) {
        int hr = h0 + r - 1;
        hr = (hr < 0) ? 1 : ((hr > 127) ? 126 : hr);
        int rowb = hr << 7;
        q[0] = *(const vf4u*)(srcb + (size_t)(((rowb + cw0) << 7) + fo));
        q[1] = *(const vf4u*)(srcb + (size_t)(((rowb + w0)  << 7) + fo));
        q[2] = *(const vf4u*)(srcb + (size_t)(((rowb + w1)  << 7) + fo));
        q[3] = *(const vf4u*)(srcb + (size_t)(((rowb + cw3) << 7) + fo));
    };

    vf4 qc[4], qn[4];
    loadrow(0, qc);

#pragma unroll
    for (int r = 0; r < 10; ++r) {
        // prefetch next row BEFORE this row's math: HBM latency hides under it
        if (r < 9) loadrow(r + 1, qn);

        // --- c-stage along d, 4 columns, no cross-lane ---
        // interior lane: v = {d-1, d, d+1, d+2}
        // lane 0  (fo=0):   v={0,1,2,3}:   L=v.y(reflect) q=(v.x,v.y) R=v.z
        // lane 63 (fo=124): v={124..127}:  L=v.y          q=(v.z,v.w) R=v.z(reflect)
        vf2 S[4], D[4], U[4];
#pragma unroll
        for (int c = 0; c < 4; ++c) {
            vf4 v = qc[c];
            float L  = le  ? v.y : v.x;
            float qx = l0 ? v.x : (l63 ? v.z : v.y);
            float qy = l0 ? v.y : (l63 ? v.w : v.z);
            float R  = le  ? v.z : v.w;
            vf2 q = {qx, qy};
            vf2 LV = {L, qx};
            vf2 RV = {qy, R};
            vf2 t = LV + RV;
            S[c] = __builtin_elementwise_fma(two, q, t);
            D[c] = RV - LV;
            U[c] = t + q;
        }

        int slot = r % 3;
#pragma unroll
        for (int o = 0; o < 2; ++o) {
            vf2 D0 = D[o], D1 = D[o + 1], D2 = D[o + 2];
            vf2 S0 = S[o], S1 = S[o + 1], S2 = S[o + 2];
            vf2 U0 = U[o], U1 = U[o + 1], U2 = U[o + 2];
            vf2 tD = D0 + D2;
            sbD[o][slot] = __builtin_elementwise_fma(two, D1, tD);
            ubD[o][slot] = tD + D1;
            vf2 tS = S0 + S2;
            sbS[o][slot] = __builtin_elementwise_fma(two, S1, tS);
            ubS[o][slot] = tS + S1;
            dbS[o][slot] = S2 - S0;
            vf2 tU = U0 + U2;
            sbU[o][slot] = __builtin_elementwise_fma(two, U1, tU);
            dbU[o][slot] = U2 - U0;
        }

        if (r >= 2) {
            int s0 = (r - 2) % 3, s1 = (r - 1) % 3, s2 = slot;
            int hout = h0 + r - 2;
#pragma unroll
            for (int o = 0; o < 2; ++o) {
                vf2 tsbD = sbD[o][s0] + sbD[o][s2];
                vf2 Gssd = __builtin_elementwise_fma(two, sbD[o][s1], tsbD);
                vf2 Gusd = tsbD + sbD[o][s1];
                vf2 tubD = ubD[o][s0] + ubD[o][s2];
                vf2 Gsud = __builtin_elementwise_fma(two, ubD[o][s1], tubD);
                vf2 tdbS = dbS[o][s0] + dbS[o][s2];
                vf2 Gsds = __builtin_elementwise_fma(two, dbS[o][s1], tdbS);
                vf2 Guds = tdbS + dbS[o][s1];
                vf2 Gdss = sbS[o][s2] - sbS[o][s0];
                vf2 Gdus = ubS[o][s2] - ubS[o][s0];
                vf2 tdbU = dbU[o][s0] + dbU[o][s2];
                vf2 Gsdu = __builtin_elementwise_fma(two, dbU[o][s1], tdbU);
                vf2 Gdsu = sbU[o][s2] - sbU[o][s0];

                // s = 9e-6 + (3 unpaired squares) + 2*(6 pair-half squares)
                vf2 s1v = {9.0f * 1e-6f, 9.0f * 1e-6f};
                s1v = __builtin_elementwise_fma(Gssd, Gssd, s1v);
                s1v = __builtin_elementwise_fma(Gsds, Gsds, s1v);
                s1v = __builtin_elementwise_fma(Gdss, Gdss, s1v);
                vf2 s2v = Gsud * Gsud;
                s2v = __builtin_elementwise_fma(Gsdu, Gsdu, s2v);
                s2v = __builtin_elementwise_fma(Gdus, Gdus, s2v);
                s2v = __builtin_elementwise_fma(Guds, Guds, s2v);
                s2v = __builtin_elementwise_fma(Gusd, Gusd, s2v);
                s2v = __builtin_elementwise_fma(Gdsu, Gdsu, s2v);
                vf2 s = __builtin_elementwise_fma(two, s2v, s1v);

                smn = __builtin_elementwise_min(smn, s);
                smx = __builtin_elementwise_max(smx, s);

                float2 m2;
                m2.x = __builtin_amdgcn_sqrtf(s.x);
                m2.y = __builtin_amdgcn_sqrtf(s.y);
                __half2 hm2 = __float22half2_rn(m2);
                int h2idx = (((b * 128 + hout) * 128 + (w0 + o)) << 6) + lane;
                __builtin_nontemporal_store(*(unsigned int*)&hm2,
                    (unsigned int*)((__half2*)dst + h2idx));
            }
        }

#pragma unroll
        for (int c = 0; c < 4; ++c) qc[c] = qn[c];
    }

    // Wave min/max reduce on s (uint trick valid: s >= 9e-6 > 0); the single
    // hardware-sqrt+half_rn round at the end reproduces the per-voxel stored
    // extreme exactly (same monotone composition commutes with min/max).
    unsigned int umn = __float_as_uint(fminf(smn.x, smn.y));
    unsigned int umx = __float_as_uint(fmaxf(smx.x, smx.y));
#pragma unroll
    for (int off = 32; off > 0; off >>= 1) {
        unsigned int a1 = __shfl_down(umn, off, 64);
        unsigned int b1 = __shfl_down(umx, off, 64);
        umn = (a1 < umn) ? a1 : umn;
        umx = (b1 > umx) ? b1 : umx;
    }
    if (lane == 0) {
        float mnm = __half2float(__float2half_rn(__builtin_amdgcn_sqrtf(__uint_as_float(umn))));
        float mxm = __half2float(__float2half_rn(__builtin_amdgcn_sqrtf(__uint_as_float(umx))));
        g_bmin[wgid] = __float_as_uint(mnm);
        g_bmax[wgid] = __float_as_uint(mxm);
    }
}

// ---------------------------------------------------------------------------
// Pass 2 (slots = 8192): every block redundantly reduces the 64 KB of min/max
// slots (LLC-resident; no fences), streams its sequential shard of both fp16
// mag arrays, one pre-scaled atomicAdd(out).
// ---------------------------------------------------------------------------
__global__ __launch_bounds__(TPB) void pass2_kernel(
    const uint4* __restrict__ magx8, const uint4* __restrict__ magy8,
    float* __restrict__ out) {
    int tid = threadIdx.x, bid = blockIdx.x;
    int lane = tid & 63, wid = tid >> 6;
    __shared__ unsigned int sred[4][4];
    __shared__ float smm[4];
    __shared__ float sv[4];

    // ---- redundant global min/max reduce: 4096 slots per image = 1024 uint4 ----
    const uint4* bmin4 = (const uint4*)g_bmin;   // [0,1024): img x, [1024,2048): img y
    const uint4* bmax4 = (const uint4*)g_bmax;
    unsigned int v0 = 0xFFFFFFFFu, v1 = 0u, v2 = 0xFFFFFFFFu, v3 = 0u;
#pragma unroll
    for (int k = 0; k < 4; ++k) {
        int idx = k * TPB + tid;
        uint4 a = bmin4[idx];
        uint4 bq = bmax4[idx];
        uint4 c = bmin4[idx + 1024];
        uint4 d = bmax4[idx + 1024];
        unsigned int a01 = (a.x < a.y) ? a.x : a.y, a23 = (a.z < a.w) ? a.z : a.w;
        unsigned int b01 = (bq.x > bq.y) ? bq.x : bq.y, b23 = (bq.z > bq.w) ? bq.z : bq.w;
        unsigned int c01 = (c.x < c.y) ? c.x : c.y, c23 = (c.z < c.w) ? c.z : c.w;
        unsigned int d01 = (d.x > d.y) ? d.x : d.y, d23 = (d.z > d.w) ? d.z : d.w;
        unsigned int t0 = (a01 < a23) ? a01 : a23;
        unsigned int t1 = (b01 > b23) ? b01 : b23;
        unsigned int t2 = (c01 < c23) ? c01 : c23;
        unsigned int t3 = (d01 > d23) ? d01 : d23;
        v0 = (t0 < v0) ? t0 : v0;
        v1 = (t1 > v1) ? t1 : v1;
        v2 = (t2 < v2) ? t2 : v2;
        v3 = (t3 > v3) ? t3 : v3;
    }
#pragma unroll
    for (int off = 32; off > 0; off >>= 1) {
        unsigned int t0 = __shfl_down(v0, off, 64);
        unsigned int t1 = __shfl_down(v1, off, 64);
        unsigned int t2 = __shfl_down(v2, off, 64);
        unsigned int t3 = __shfl_down(v3, off, 64);
        v0 = (t0 < v0) ? t0 : v0;
        v1 = (t1 > v1) ? t1 : v1;
        v2 = (t2 < v2) ? t2 : v2;
        v3 = (t3 > v3) ? t3 : v3;
    }
    if (lane == 0) { sred[wid][0] = v0; sred[wid][1] = v1; sred[wid][2] = v2; sred[wid][3] = v3; }
    __syncthreads();
    if (tid == 0) {
        unsigned int r0 = sred[0][0], r1 = sred[0][1], r2 = sred[0][2], r3 = sred[0][3];
#pragma unroll
        for (int w = 1; w < 4; ++w) {
            r0 = (sred[w][0] < r0) ? sred[w][0] : r0;
            r1 = (sred[w][1] > r1) ? sred[w][1] : r1;
            r2 = (sred[w][2] < r2) ? sred[w][2] : r2;
            r3 = (sred[w][3] > r3) ? sred[w][3] : r3;
        }
        smm[0] = __uint_as_float(r0);
        smm[1] = __uint_as_float(r1);
        smm[2] = __uint_as_float(r2);
        smm[3] = __uint_as_float(r3);
    }
    __syncthreads();

    // ---- normalize + L1 partial sum over this block's sequential shard ----
    float mnx = smm[0], mxx = smm[1], mny = smm[2], mxy = smm[3];
    float ix = 1.0f / (mxx - mnx + 1e-6f);
    float iy = 1.0f / (mxy - mny + 1e-6f);
    float cx = -mnx * ix;
    float cy = -mny * iy;

    float s = 0.0f;
    // NVOX/8 = 1,048,576 uint4 per array; per block 2048 sequential uint4
#pragma unroll
    for (int k = 0; k < 8; ++k) {
        int i = bid * 2048 + k * TPB + tid;
        U4H8 qa, qb;
        qa.u = magx8[i];
        qb.u = magy8[i];
#pragma unroll
        for (int j = 0; j < 4; ++j) {
            float2 va = __half22float2(qa.h[j]);
            float2 vb = __half22float2(qb.h[j]);
            s += fabsf(fmaf(va.x, ix, cx) - fmaf(vb.x, iy, cy));
            s += fabsf(fmaf(va.y, ix, cx) - fmaf(vb.y, iy, cy));
        }
    }
#pragma unroll
    for (int off = 32; off > 0; off >>= 1) s += __shfl_down(s, off, 64);
    if (lane == 0) sv[wid] = s;
    __syncthreads();
    if (tid == 0) {
        float partial = ((sv[0] + sv[1]) + (sv[2] + sv[3])) * (1.0f / (float)NVOX); // *2^-23 exact
        if (bid == 0) partial += 1e-6f;
        atomicAdd(out, partial);
    }
}

extern "C" void kernel_launch(void* const* d_in, const int* in_sizes, int n_in,
                              void* d_out, int out_size, void* d_ws, size_t ws_size,
                              hipStream_t stream) {
    const float* x = (const float*)d_in[0];
    const float* y = (const float*)d_in[1];
    // d_in[2] = kernels (weights hardcoded via separable factorization)
    float* out = (float*)d_out;

    __half* magx = (__half*)d_ws;            // NVOX halfs (16 MiB)
    __half* magy = magx + NVOX;              // NVOX halfs (16 MiB)

    pass1_kernel<<<NBLK1, 64, 0, stream>>>(x, y, magx, magy, out);
    pass2_kernel<<<GRID2, TPB, 0, stream>>>((const uint4*)magx, (const uint4*)magy, out);
}

// Round 7
// 128.290 us; speedup vs baseline: 1.0152x; 1.0152x over previous
//
#include <hip/hip_runtime.h>
#include <hip/hip_fp16.h>

#define HH 128
#define NB 4
#define NVOX (NB * HH * HH * HH)   // 8,388,608 = 2^23 voxels per image

// pass1 v12: v9b (127.7us champion: shfl halo, depth-1 prefetch, raw v_sqrt,
// pair-square epilogue, pre-sqrt min/max) + (a) inline-asm v_pk_*_f32 for all
// vf2 math (counter arithmetic says ~330 VALU instr/row vs ~140 if packed ->
// hipcc is scalarizing the ext_vector float2 ops; CDNA4 packed fp32 is full
// rate and bit-identical per element), + (b) hashed per-block s_sleep stagger
// (0-448cy) after first loads: co-resident waves run identical code in
// lockstep, so their memory stalls align; jitter lets one wave's compute
// cover another's stall (VALUBusy was 51% with 8 waves/SIMD resident).
#define NBLK1 2048                 // img2 * b4 * hstrip16 * wgroup16
#define GRID2 512
#define TPB 256

typedef float vf2 __attribute__((ext_vector_type(2)));

// packed-fp32 helpers: semantics identical to elementwise fma/add/sub/mul
static __device__ __forceinline__ vf2 pk_fma(vf2 a, vf2 b, vf2 c) {
    vf2 d; asm("v_pk_fma_f32 %0, %1, %2, %3" : "=v"(d) : "v"(a), "v"(b), "v"(c)); return d;
}
static __device__ __forceinline__ vf2 pk_add(vf2 a, vf2 b) {
    vf2 d; asm("v_pk_add_f32 %0, %1, %2" : "=v"(d) : "v"(a), "v"(b)); return d;
}
static __device__ __forceinline__ vf2 pk_sub(vf2 a, vf2 b) {   // a - b
    vf2 d; asm("v_pk_add_f32 %0, %1, %2 neg_lo:[0,1] neg_hi:[0,1]" : "=v"(d) : "v"(a), "v"(b)); return d;
}
static __device__ __forceinline__ vf2 pk_mul(vf2 a, vf2 b) {
    vf2 d; asm("v_pk_mul_f32 %0, %1, %2" : "=v"(d) : "v"(a), "v"(b)); return d;
}

// Slot arrays: every slot written by pass1 every call before pass2 reads them
// (dispatch-boundary ordering). No init kernel, no atomics on these.
__device__ __align__(16) unsigned int g_bmin[NBLK1];
__device__ __align__(16) unsigned int g_bmax[NBLK1];

union U4H8 { uint4 u; __half2 h[4]; };

// ---------------------------------------------------------------------------
// Pass 1 (register/shfl, packed fp32, 2 cols/wave, no LDS).
// Ops per axis: s=(1,2,1), d=(-1,0,1), u=(1,1,1).
//   Sx=Gssd Sy=Gsds Sz=Gdss ; Sd11=Gsud-Gsdu Sd12=Gsud+Gsdu
//   Sd21=Gdus-Guds Sd22=Gdus+Guds ; Sd31=Gusd-Gdsu Sd32=Gusd+Gdsu
// Pair identity: (A-B)^2+(A+B)^2 = 2A^2+2B^2, so only 9 G-quantities matter:
//   s = 9e-6 + Gssd^2+Gsds^2+Gdss^2 + 2[Gsud^2+Gsdu^2+Gdus^2+Guds^2+Gusd^2+Gdsu^2]
// Reflect pad=1: -1 -> 1, 128 -> 126. h,w wave-uniform; d via lane-selects.
// ---------------------------------------------------------------------------
__global__ __launch_bounds__(256) void pass1_kernel(
    const float* __restrict__ x, const float* __restrict__ y,
    __half* __restrict__ magx, __half* __restrict__ magy,
    float* __restrict__ out) {
    int bid = blockIdx.x;
    int tid = threadIdx.x;
    if (bid == 0 && tid == 0) out[0] = 0.0f;   // poison-clear for pass2 atomics

    int lane = tid & 63, wid = tid >> 6;
    int wg  = bid & 15;
    int hs  = (bid >> 4) & 15;
    int b   = (bid >> 8) & 3;
    int img = bid >> 10;

    const float* __restrict__ src = img ? y : x;
    __half* __restrict__ dst = img ? magy : magx;

    int w0 = wg * 8 + wid * 2;         // first output column (even)
    int w1 = w0 + 1;                   // second output column
    int cw0 = (w0 == 0) ? 1 : (w0 - 1);
    int cw3 = (w1 == 127) ? 126 : (w1 + 1);
    int h0 = hs << 3;                  // 8 output rows per block
    const vf2* base2 = (const vf2*)(src + ((size_t)b << 21));

    const vf2 two = {2.0f, 2.0f};

    // ring state per output column: 7 vf2 quantities x 3 slots
    vf2 sbD[2][3], ubD[2][3], dbS[2][3], sbS[2][3], ubS[2][3], dbU[2][3], sbU[2][3];
    vf2 smn = {3.4e38f, 3.4e38f};      // min/max tracked on s (pre-sqrt)
    vf2 smx = {0.0f, 0.0f};
    bool l0 = (lane == 0), l63 = (lane == 63);

    auto loadrow = [&](int r, vf2* q) {
        int hr = h0 + r - 1;
        hr = (hr < 0) ? 1 : ((hr > 127) ? 126 : hr);
        int rowb = (hr << 7);
        q[0] = base2[(size_t)((rowb + cw0) << 6) + lane];
        q[1] = base2[(size_t)((rowb + w0)  << 6) + lane];
        q[2] = base2[(size_t)((rowb + w1)  << 6) + lane];
        q[3] = base2[(size_t)((rowb + cw3) << 6) + lane];
    };

    vf2 qc[4], qn[4];
    loadrow(0, qc);

    // desynchronize co-resident waves: hashed 0..7 x 64cy sleep while the
    // first row's loads are in flight (wave-uniform branch, one-time cost)
    switch ((unsigned)(bid * 2654435761u + wid * 40503u) >> 29) {
        case 1: __builtin_amdgcn_s_sleep(1); break;
        case 2: __builtin_amdgcn_s_sleep(2); break;
        case 3: __builtin_amdgcn_s_sleep(3); break;
        case 4: __builtin_amdgcn_s_sleep(4); break;
        case 5: __builtin_amdgcn_s_sleep(5); break;
        case 6: __builtin_amdgcn_s_sleep(6); break;
        case 7: __builtin_amdgcn_s_sleep(7); break;
        default: break;
    }

#pragma unroll
    for (int r = 0; r < 10; ++r) {
        // prefetch next row BEFORE this row's math: HBM latency hides under it
        if (r < 9) loadrow(r + 1, qn);

        // --- c-stage along d for 4 columns: shuffles first, then combines ---
        float Lup[4], Rdn[4];
#pragma unroll
        for (int c = 0; c < 4; ++c) {
            Lup[c] = __shfl_up(qc[c].y, 1);
            Rdn[c] = __shfl_down(qc[c].x, 1);
        }
        vf2 S[4], D[4], U[4];
#pragma unroll
        for (int c = 0; c < 4; ++c) {
            float Lx = l0  ? qc[c].y : Lup[c];   // d=2i-1 (reflect d=0 -> q[1])
            float Ry = l63 ? qc[c].x : Rdn[c];   // d=2i+2 (reflect d=127 -> q[126])
            vf2 LV = {Lx, qc[c].x};
            vf2 RV = {qc[c].y, Ry};
            vf2 t = pk_add(LV, RV);
            S[c] = pk_fma(two, qc[c], t);
            D[c] = pk_sub(RV, LV);
            U[c] = pk_add(t, qc[c]);
        }

        int slot = r % 3;
#pragma unroll
        for (int o = 0; o < 2; ++o) {
            vf2 D0 = D[o], D1 = D[o + 1], D2 = D[o + 2];
            vf2 S0 = S[o], S1 = S[o + 1], S2 = S[o + 2];
            vf2 U0 = U[o], U1 = U[o + 1], U2 = U[o + 2];
            vf2 tD = pk_add(D0, D2);
            sbD[o][slot] = pk_fma(two, D1, tD);
            ubD[o][slot] = pk_add(tD, D1);
            vf2 tS = pk_add(S0, S2);
            sbS[o][slot] = pk_fma(two, S1, tS);
            ubS[o][slot] = pk_add(tS, S1);
            dbS[o][slot] = pk_sub(S2, S0);
            vf2 tU = pk_add(U0, U2);
            sbU[o][slot] = pk_fma(two, U1, tU);
            dbU[o][slot] = pk_sub(U2, U0);
        }

        if (r >= 2) {
            int s0 = (r - 2) % 3, s1 = (r - 1) % 3, s2 = slot;
            int hout = h0 + r - 2;
#pragma unroll
            for (int o = 0; o < 2; ++o) {
                vf2 tsbD = pk_add(sbD[o][s0], sbD[o][s2]);
                vf2 Gssd = pk_fma(two, sbD[o][s1], tsbD);
                vf2 Gusd = pk_add(tsbD, sbD[o][s1]);
                vf2 tubD = pk_add(ubD[o][s0], ubD[o][s2]);
                vf2 Gsud = pk_fma(two, ubD[o][s1], tubD);
                vf2 tdbS = pk_add(dbS[o][s0], dbS[o][s2]);
                vf2 Gsds = pk_fma(two, dbS[o][s1], tdbS);
                vf2 Guds = pk_add(tdbS, dbS[o][s1]);
                vf2 Gdss = pk_sub(sbS[o][s2], sbS[o][s0]);
                vf2 Gdus = pk_sub(ubS[o][s2], ubS[o][s0]);
                vf2 tdbU = pk_add(dbU[o][s0], dbU[o][s2]);
                vf2 Gsdu = pk_fma(two, dbU[o][s1], tdbU);
                vf2 Gdsu = pk_sub(sbU[o][s2], sbU[o][s0]);

                // s = 9e-6 + (3 unpaired squares) + 2*(6 pair-half squares)
                vf2 s1v = {9.0f * 1e-6f, 9.0f * 1e-6f};
                s1v = pk_fma(Gssd, Gssd, s1v);
                s1v = pk_fma(Gsds, Gsds, s1v);
                s1v = pk_fma(Gdss, Gdss, s1v);
                vf2 s2v = pk_mul(Gsud, Gsud);
                s2v = pk_fma(Gsdu, Gsdu, s2v);
                s2v = pk_fma(Gdus, Gdus, s2v);
                s2v = pk_fma(Guds, Guds, s2v);
                s2v = pk_fma(Gusd, Gusd, s2v);
                s2v = pk_fma(Gdsu, Gdsu, s2v);
                vf2 s = pk_fma(two, s2v, s1v);

                smn = __builtin_elementwise_min(smn, s);
                smx = __builtin_elementwise_max(smx, s);

                float2 m2;
                m2.x = __builtin_amdgcn_sqrtf(s.x);
                m2.y = __builtin_amdgcn_sqrtf(s.y);
                __half2 hm2 = __float22half2_rn(m2);
                int h2idx = (((b * 128 + hout) * 128 + (w0 + o)) << 6) + lane;
                __builtin_nontemporal_store(*(unsigned int*)&hm2,
                    (unsigned int*)((__half2*)dst + h2idx));
            }
        }

#pragma unroll
        for (int c = 0; c < 4; ++c) qc[c] = qn[c];
    }

    // Block min/max reduce on s (uint trick valid: s >= 9e-6 > 0); the single
    // hardware-sqrt+half_rn round at the end reproduces the per-voxel stored
    // extreme exactly (same monotone composition commutes with min/max).
    unsigned int umn = __float_as_uint(fminf(smn.x, smn.y));
    unsigned int umx = __float_as_uint(fmaxf(smx.x, smx.y));
#pragma unroll
    for (int off = 32; off > 0; off >>= 1) {
        unsigned int a1 = __shfl_down(umn, off, 64);
        unsigned int b1 = __shfl_down(umx, off, 64);
        umn = (a1 < umn) ? a1 : umn;
        umx = (b1 > umx) ? b1 : umx;
    }
    __shared__ unsigned int smnsh[4], smxsh[4];
    if (lane == 0) { smnsh[wid] = umn; smxsh[wid] = umx; }
    __syncthreads();
    if (tid == 0) {
        unsigned int m0 = smnsh[0] < smnsh[1] ? smnsh[0] : smnsh[1];
        unsigned int m1 = smnsh[2] < smnsh[3] ? smnsh[2] : smnsh[3];
        unsigned int x0 = smxsh[0] > smxsh[1] ? smxsh[0] : smxsh[1];
        unsigned int x1 = smxsh[2] > smxsh[3] ? smxsh[2] : smxsh[3];
        float ms = __uint_as_float(m0 < m1 ? m0 : m1);
        float xs = __uint_as_float(x0 > x1 ? x0 : x1);
        float mnm = __half2float(__float2half_rn(__builtin_amdgcn_sqrtf(ms)));
        float mxm = __half2float(__float2half_rn(__builtin_amdgcn_sqrtf(xs)));
        g_bmin[bid] = __float_as_uint(mnm);
        g_bmax[bid] = __float_as_uint(mxm);
    }
}

// ---------------------------------------------------------------------------
// Pass 2 (R10-proven, slots = 2048): every block redundantly reduces the 16 KB
// of min/max slots (LLC-resident; no fences), streams its sequential shard of
// both fp16 mag arrays, one pre-scaled atomicAdd(out).
// ---------------------------------------------------------------------------
__global__ __launch_bounds__(TPB) void pass2_kernel(
    const uint4* __restrict__ magx8, const uint4* __restrict__ magy8,
    float* __restrict__ out) {
    int tid = threadIdx.x, bid = blockIdx.x;
    int lane = tid & 63, wid = tid >> 6;
    __shared__ unsigned int sred[4][4];
    __shared__ float smm[4];
    __shared__ float sv[4];

    // ---- redundant global min/max reduce: 1024 slots per image = 256 uint4 ----
    const uint4* bmin4 = (const uint4*)g_bmin;   // [0,256): img x, [256,512): img y
    const uint4* bmax4 = (const uint4*)g_bmax;
    uint4 a = bmin4[tid];
    uint4 bq = bmax4[tid];
    uint4 c = bmin4[tid + 256];
    uint4 d = bmax4[tid + 256];
    unsigned int a01 = (a.x < a.y) ? a.x : a.y, a23 = (a.z < a.w) ? a.z : a.w;
    unsigned int b01 = (bq.x > bq.y) ? bq.x : bq.y, b23 = (bq.z > bq.w) ? bq.z : bq.w;
    unsigned int c01 = (c.x < c.y) ? c.x : c.y, c23 = (c.z < c.w) ? c.z : c.w;
    unsigned int d01 = (d.x > d.y) ? d.x : d.y, d23 = (d.z > d.w) ? d.z : d.w;
    unsigned int v0 = (a01 < a23) ? a01 : a23;
    unsigned int v1 = (b01 > b23) ? b01 : b23;
    unsigned int v2 = (c01 < c23) ? c01 : c23;
    unsigned int v3 = (d01 > d23) ? d01 : d23;
#pragma unroll
    for (int off = 32; off > 0; off >>= 1) {
        unsigned int t0 = __shfl_down(v0, off, 64);
        unsigned int t1 = __shfl_down(v1, off, 64);
        unsigned int t2 = __shfl_down(v2, off, 64);
        unsigned int t3 = __shfl_down(v3, off, 64);
        v0 = (t0 < v0) ? t0 : v0;
        v1 = (t1 > v1) ? t1 : v1;
        v2 = (t2 < v2) ? t2 : v2;
        v3 = (t3 > v3) ? t3 : v3;
    }
    if (lane == 0) { sred[wid][0] = v0; sred[wid][1] = v1; sred[wid][2] = v2; sred[wid][3] = v3; }
    __syncthreads();
    if (tid == 0) {
        unsigned int r0 = sred[0][0], r1 = sred[0][1], r2 = sred[0][2], r3 = sred[0][3];
#pragma unroll
        for (int w = 1; w < 4; ++w) {
            r0 = (sred[w][0] < r0) ? sred[w][0] : r0;
            r1 = (sred[w][1] > r1) ? sred[w][1] : r1;
            r2 = (sred[w][2] < r2) ? sred[w][2] : r2;
            r3 = (sred[w][3] > r3) ? sred[w][3] : r3;
        }
        smm[0] = __uint_as_float(r0);
        smm[1] = __uint_as_float(r1);
        smm[2] = __uint_as_float(r2);
        smm[3] = __uint_as_float(r3);
    }
    __syncthreads();

    // ---- normalize + L1 partial sum over this block's sequential shard ----
    float mnx = smm[0], mxx = smm[1], mny = smm[2], mxy = smm[3];
    float ix = 1.0f / (mxx - mnx + 1e-6f);
    float iy = 1.0f / (mxy - mny + 1e-6f);
    float cx = -mnx * ix;
    float cy = -mny * iy;

    float s = 0.0f;
    // NVOX/8 = 1,048,576 uint4 per array; per block 2048 sequential uint4
#pragma unroll
    for (int k = 0; k < 8; ++k) {
        int i = bid * 2048 + k * TPB + tid;
        U4H8 qa, qb;
        qa.u = magx8[i];
        qb.u = magy8[i];
#pragma unroll
        for (int j = 0; j < 4; ++j) {
            float2 va = __half22float2(qa.h[j]);
            float2 vb = __half22float2(qb.h[j]);
            s += fabsf(fmaf(va.x, ix, cx) - fmaf(vb.x, iy, cy));
            s += fabsf(fmaf(va.y, ix, cx) - fmaf(vb.y, iy, cy));
        }
    }
#pragma unroll
    for (int off = 32; off > 0; off >>= 1) s += __shfl_down(s, off, 64);
    if (lane == 0) sv[wid] = s;
    __syncthreads();
    if (tid == 0) {
        float partial = ((sv[0] + sv[1]) + (sv[2] + sv[3])) * (1.0f / (float)NVOX); // *2^-23 exact
        if (bid == 0) partial += 1e-6f;
        atomicAdd(out, partial);
    }
}

extern "C" void kernel_launch(void* const* d_in, const int* in_sizes, int n_in,
                              void* d_out, int out_size, void* d_ws, size_t ws_size,
                              hipStream_t stream) {
    const float* x = (const float*)d_in[0];
    const float* y = (const float*)d_in[1];
    // d_in[2] = kernels (weights hardcoded via separable factorization)
    float* out = (float*)d_out;

    __half* magx = (__half*)d_ws;            // NVOX halfs (16 MiB)
    __half* magy = magx + NVOX;              // NVOX halfs (16 MiB)

    pass1_kernel<<<NBLK1, 256, 0, stream>>>(x, y, magx, magy, out);
    pass2_kernel<<<GRID2, TPB, 0, stream>>>((const uint4*)magx, (const uint4*)magy, out);
}

// Round 8
// 127.353 us; speedup vs baseline: 1.0227x; 1.0074x over previous
//
#include <hip/hip_runtime.h>
#include <hip/hip_fp16.h>

#define HH 128
#define NB 4
#define NVOX (NB * HH * HH * HH)   // 8,388,608 = 2^23 voxels per image

// pass1 v13: v9b champion math with a ROLLED row loop (#pragma unroll 1) +
// explicit 3-slot register rotation. Rationale: R0-R7 showed pass1 invariant
// (38-43us) to waves/block, halo mechanism, grid, XCD swizzle, packed-vs-
// scalar VALU, and wave stagger -> not bound by any of those. The one shared
// structural property was the fully-unrolled 10-row body (~26 KB of code,
// at/past per-CU I$ capacity; fetch-starved issue matches VALUBusy~51%
// stuck + occupancy~30%). Rolled body ~3 KB. Rotation uses only literal
// indices (no dynamic vf2 array indexing -> no scratch).
#define NBLK1 2048                 // img2 * b4 * hstrip16 * wgroup16
#define GRID2 512
#define TPB 256

typedef float vf2 __attribute__((ext_vector_type(2)));

// Slot arrays: every slot written by pass1 every call before pass2 reads them
// (dispatch-boundary ordering). No init kernel, no atomics on these.
__device__ __align__(16) unsigned int g_bmin[NBLK1];
__device__ __align__(16) unsigned int g_bmax[NBLK1];

union U4H8 { uint4 u; __half2 h[4]; };

// ---------------------------------------------------------------------------
// Pass 1 (register/shfl, packed fp32, 2 cols/wave, no LDS).
// Ops per axis: s=(1,2,1), d=(-1,0,1), u=(1,1,1).
//   Sx=Gssd Sy=Gsds Sz=Gdss ; Sd11=Gsud-Gsdu Sd12=Gsud+Gsdu
//   Sd21=Gdus-Guds Sd22=Gdus+Guds ; Sd31=Gusd-Gdsu Sd32=Gusd+Gdsu
// Pair identity: (A-B)^2+(A+B)^2 = 2A^2+2B^2, so only 9 G-quantities matter:
//   s = 9e-6 + Gssd^2+Gsds^2+Gdss^2 + 2[Gsud^2+Gsdu^2+Gdus^2+Guds^2+Gusd^2+Gdsu^2]
// Reflect pad=1: -1 -> 1, 128 -> 126. h,w wave-uniform; d via lane-selects.
// Rolled loop: slot0 = row r-2, slot1 = row r-1, slot2 = row r (rotated).
// ---------------------------------------------------------------------------
__global__ __launch_bounds__(256) void pass1_kernel(
    const float* __restrict__ x, const float* __restrict__ y,
    __half* __restrict__ magx, __half* __restrict__ magy,
    float* __restrict__ out) {
    int bid = blockIdx.x;
    int tid = threadIdx.x;
    if (bid == 0 && tid == 0) out[0] = 0.0f;   // poison-clear for pass2 atomics

    int lane = tid & 63, wid = tid >> 6;
    int wg  = bid & 15;
    int hs  = (bid >> 4) & 15;
    int b   = (bid >> 8) & 3;
    int img = bid >> 10;

    const float* __restrict__ src = img ? y : x;
    __half* __restrict__ dst = img ? magy : magx;

    int w0 = wg * 8 + wid * 2;         // first output column (even)
    int w1 = w0 + 1;                   // second output column
    int cw0 = (w0 == 0) ? 1 : (w0 - 1);
    int cw3 = (w1 == 127) ? 126 : (w1 + 1);
    int h0 = hs << 3;                  // 8 output rows per block
    const vf2* base2 = (const vf2*)(src + ((size_t)b << 21));

    const vf2 two = {2.0f, 2.0f};

    // ring state per output column: 7 vf2 quantities x 3 slots (literal idx)
    vf2 sbD[2][3], ubD[2][3], dbS[2][3], sbS[2][3], ubS[2][3], dbU[2][3], sbU[2][3];
    vf2 smn = {3.4e38f, 3.4e38f};      // min/max tracked on s (pre-sqrt)
    vf2 smx = {0.0f, 0.0f};
    bool l0 = (lane == 0), l63 = (lane == 63);

    auto loadrow = [&](int r, vf2* q) {
        int hr = h0 + r - 1;
        hr = (hr < 0) ? 1 : ((hr > 127) ? 126 : hr);
        int rowb = (hr << 7);
        q[0] = base2[(size_t)((rowb + cw0) << 6) + lane];
        q[1] = base2[(size_t)((rowb + w0)  << 6) + lane];
        q[2] = base2[(size_t)((rowb + w1)  << 6) + lane];
        q[3] = base2[(size_t)((rowb + cw3) << 6) + lane];
    };

    vf2 qc[4], qn[4], S[4], D[4], U[4];

    // c-stage along d for 4 columns (shuffles first, then combines)
    auto cstage_all = [&]() {
        float Lup[4], Rdn[4];
#pragma unroll
        for (int c = 0; c < 4; ++c) {
            Lup[c] = __shfl_up(qc[c].y, 1);
            Rdn[c] = __shfl_down(qc[c].x, 1);
        }
#pragma unroll
        for (int c = 0; c < 4; ++c) {
            float Lx = l0  ? qc[c].y : Lup[c];   // d=2i-1 (reflect d=0 -> q[1])
            float Ry = l63 ? qc[c].x : Rdn[c];   // d=2i+2 (reflect d=127 -> q[126])
            vf2 LV = {Lx, qc[c].x};
            vf2 RV = {qc[c].y, Ry};
            vf2 t = LV + RV;
            S[c] = __builtin_elementwise_fma(two, qc[c], t);
            D[c] = RV - LV;
            U[c] = t + qc[c];
        }
    };

    // stage S/D/U into ring slot (slot is a compile-time literal at call sites)
    auto stage = [&](int slot) {
#pragma unroll
        for (int o = 0; o < 2; ++o) {
            vf2 D0 = D[o], D1 = D[o + 1], D2 = D[o + 2];
            vf2 S0 = S[o], S1 = S[o + 1], S2 = S[o + 2];
            vf2 U0 = U[o], U1 = U[o + 1], U2 = U[o + 2];
            vf2 tD = D0 + D2;
            sbD[o][slot] = __builtin_elementwise_fma(two, D1, tD);
            ubD[o][slot] = tD + D1;
            vf2 tS = S0 + S2;
            sbS[o][slot] = __builtin_elementwise_fma(two, S1, tS);
            ubS[o][slot] = tS + S1;
            dbS[o][slot] = S2 - S0;
            vf2 tU = U0 + U2;
            sbU[o][slot] = __builtin_elementwise_fma(two, U1, tU);
            dbU[o][slot] = U2 - U0;
        }
    };

    // ---- prologue: rows 0,1 into slots 0,1 ----
    loadrow(0, qc);
    loadrow(1, qn);
    cstage_all(); stage(0);
#pragma unroll
    for (int c = 0; c < 4; ++c) qc[c] = qn[c];
    loadrow(2, qn);
    cstage_all(); stage(1);
#pragma unroll
    for (int c = 0; c < 4; ++c) qc[c] = qn[c];

    // ---- rolled main loop: rows 2..9, one output row each ----
#pragma unroll 1
    for (int r = 2; r < 10; ++r) {
        if (r < 9) loadrow(r + 1, qn);   // prefetch next row under this math
        cstage_all();
        stage(2);

        int hout = h0 + r - 2;
#pragma unroll
        for (int o = 0; o < 2; ++o) {
            vf2 tsbD = sbD[o][0] + sbD[o][2];
            vf2 Gssd = __builtin_elementwise_fma(two, sbD[o][1], tsbD);
            vf2 Gusd = tsbD + sbD[o][1];
            vf2 tubD = ubD[o][0] + ubD[o][2];
            vf2 Gsud = __builtin_elementwise_fma(two, ubD[o][1], tubD);
            vf2 tdbS = dbS[o][0] + dbS[o][2];
            vf2 Gsds = __builtin_elementwise_fma(two, dbS[o][1], tdbS);
            vf2 Guds = tdbS + dbS[o][1];
            vf2 Gdss = sbS[o][2] - sbS[o][0];
            vf2 Gdus = ubS[o][2] - ubS[o][0];
            vf2 tdbU = dbU[o][0] + dbU[o][2];
            vf2 Gsdu = __builtin_elementwise_fma(two, dbU[o][1], tdbU);
            vf2 Gdsu = sbU[o][2] - sbU[o][0];

            // s = 9e-6 + (3 unpaired squares) + 2*(6 pair-half squares)
            vf2 s1v = {9.0f * 1e-6f, 9.0f * 1e-6f};
            s1v = __builtin_elementwise_fma(Gssd, Gssd, s1v);
            s1v = __builtin_elementwise_fma(Gsds, Gsds, s1v);
            s1v = __builtin_elementwise_fma(Gdss, Gdss, s1v);
            vf2 s2v = Gsud * Gsud;
            s2v = __builtin_elementwise_fma(Gsdu, Gsdu, s2v);
            s2v = __builtin_elementwise_fma(Gdus, Gdus, s2v);
            s2v = __builtin_elementwise_fma(Guds, Guds, s2v);
            s2v = __builtin_elementwise_fma(Gusd, Gusd, s2v);
            s2v = __builtin_elementwise_fma(Gdsu, Gdsu, s2v);
            vf2 s = __builtin_elementwise_fma(two, s2v, s1v);

            smn = __builtin_elementwise_min(smn, s);
            smx = __builtin_elementwise_max(smx, s);

            float2 m2;
            m2.x = __builtin_amdgcn_sqrtf(s.x);
            m2.y = __builtin_amdgcn_sqrtf(s.y);
            __half2 hm2 = __float22half2_rn(m2);
            int h2idx = (((b * 128 + hout) * 128 + (w0 + o)) << 6) + lane;
            __builtin_nontemporal_store(*(unsigned int*)&hm2,
                (unsigned int*)((__half2*)dst + h2idx));
        }

        // rotate ring: slot0 <- slot1 <- slot2 (literal indices only)
#pragma unroll
        for (int o = 0; o < 2; ++o) {
            sbD[o][0] = sbD[o][1]; sbD[o][1] = sbD[o][2];
            ubD[o][0] = ubD[o][1]; ubD[o][1] = ubD[o][2];
            dbS[o][0] = dbS[o][1]; dbS[o][1] = dbS[o][2];
            sbS[o][0] = sbS[o][1]; sbS[o][1] = sbS[o][2];
            ubS[o][0] = ubS[o][1]; ubS[o][1] = ubS[o][2];
            dbU[o][0] = dbU[o][1]; dbU[o][1] = dbU[o][2];
            sbU[o][0] = sbU[o][1]; sbU[o][1] = sbU[o][2];
        }
#pragma unroll
        for (int c = 0; c < 4; ++c) qc[c] = qn[c];
    }

    // Block min/max reduce on s (uint trick valid: s >= 9e-6 > 0); the single
    // hardware-sqrt+half_rn round at the end reproduces the per-voxel stored
    // extreme exactly (same monotone composition commutes with min/max).
    unsigned int umn = __float_as_uint(fminf(smn.x, smn.y));
    unsigned int umx = __float_as_uint(fmaxf(smx.x, smx.y));
#pragma unroll
    for (int off = 32; off > 0; off >>= 1) {
        unsigned int a1 = __shfl_down(umn, off, 64);
        unsigned int b1 = __shfl_down(umx, off, 64);
        umn = (a1 < umn) ? a1 : umn;
        umx = (b1 > umx) ? b1 : umx;
    }
    __shared__ unsigned int smnsh[4], smxsh[4];
    if (lane == 0) { smnsh[wid] = umn; smxsh[wid] = umx; }
    __syncthreads();
    if (tid == 0) {
        unsigned int m0 = smnsh[0] < smnsh[1] ? smnsh[0] : smnsh[1];
        unsigned int m1 = smnsh[2] < smnsh[3] ? smnsh[2] : smnsh[3];
        unsigned int x0 = smxsh[0] > smxsh[1] ? smxsh[0] : smxsh[1];
        unsigned int x1 = smxsh[2] > smxsh[3] ? smxsh[2] : smxsh[3];
        float ms = __uint_as_float(m0 < m1 ? m0 : m1);
        float xs = __uint_as_float(x0 > x1 ? x0 : x1);
        float mnm = __half2float(__float2half_rn(__builtin_amdgcn_sqrtf(ms)));
        float mxm = __half2float(__float2half_rn(__builtin_amdgcn_sqrtf(xs)));
        g_bmin[bid] = __float_as_uint(mnm);
        g_bmax[bid] = __float_as_uint(mxm);
    }
}

// ---------------------------------------------------------------------------
// Pass 2 (R10-proven, slots = 2048): every block redundantly reduces the 16 KB
// of min/max slots (LLC-resident; no fences), streams its sequential shard of
// both fp16 mag arrays, one pre-scaled atomicAdd(out).
// ---------------------------------------------------------------------------
__global__ __launch_bounds__(TPB) void pass2_kernel(
    const uint4* __restrict__ magx8, const uint4* __restrict__ magy8,
    float* __restrict__ out) {
    int tid = threadIdx.x, bid = blockIdx.x;
    int lane = tid & 63, wid = tid >> 6;
    __shared__ unsigned int sred[4][4];
    __shared__ float smm[4];
    __shared__ float sv[4];

    // ---- redundant global min/max reduce: 1024 slots per image = 256 uint4 ----
    const uint4* bmin4 = (const uint4*)g_bmin;   // [0,256): img x, [256,512): img y
    const uint4* bmax4 = (const uint4*)g_bmax;
    uint4 a = bmin4[tid];
    uint4 bq = bmax4[tid];
    uint4 c = bmin4[tid + 256];
    uint4 d = bmax4[tid + 256];
    unsigned int a01 = (a.x < a.y) ? a.x : a.y, a23 = (a.z < a.w) ? a.z : a.w;
    unsigned int b01 = (bq.x > bq.y) ? bq.x : bq.y, b23 = (bq.z > bq.w) ? bq.z : bq.w;
    unsigned int c01 = (c.x < c.y) ? c.x : c.y, c23 = (c.z < c.w) ? c.z : c.w;
    unsigned int d01 = (d.x > d.y) ? d.x : d.y, d23 = (d.z > d.w) ? d.z : d.w;
    unsigned int v0 = (a01 < a23) ? a01 : a23;
    unsigned int v1 = (b01 > b23) ? b01 : b23;
    unsigned int v2 = (c01 < c23) ? c01 : c23;
    unsigned int v3 = (d01 > d23) ? d01 : d23;
#pragma unroll
    for (int off = 32; off > 0; off >>= 1) {
        unsigned int t0 = __shfl_down(v0, off, 64);
        unsigned int t1 = __shfl_down(v1, off, 64);
        unsigned int t2 = __shfl_down(v2, off, 64);
        unsigned int t3 = __shfl_down(v3, off, 64);
        v0 = (t0 < v0) ? t0 : v0;
        v1 = (t1 > v1) ? t1 : v1;
        v2 = (t2 < v2) ? t2 : v2;
        v3 = (t3 > v3) ? t3 : v3;
    }
    if (lane == 0) { sred[wid][0] = v0; sred[wid][1] = v1; sred[wid][2] = v2; sred[wid][3] = v3; }
    __syncthreads();
    if (tid == 0) {
        unsigned int r0 = sred[0][0], r1 = sred[0][1], r2 = sred[0][2], r3 = sred[0][3];
#pragma unroll
        for (int w = 1; w < 4; ++w) {
            r0 = (sred[w][0] < r0) ? sred[w][0] : r0;
            r1 = (sred[w][1] > r1) ? sred[w][1] : r1;
            r2 = (sred[w][2] < r2) ? sred[w][2] : r2;
            r3 = (sred[w][3] > r3) ? sred[w][3] : r3;
        }
        smm[0] = __uint_as_float(r0);
        smm[1] = __uint_as_float(r1);
        smm[2] = __uint_as_float(r2);
        smm[3] = __uint_as_float(r3);
    }
    __syncthreads();

    // ---- normalize + L1 partial sum over this block's sequential shard ----
    float mnx = smm[0], mxx = smm[1], mny = smm[2], mxy = smm[3];
    float ix = 1.0f / (mxx - mnx + 1e-6f);
    float iy = 1.0f / (mxy - mny + 1e-6f);
    float cx = -mnx * ix;
    float cy = -mny * iy;

    float s = 0.0f;
    // NVOX/8 = 1,048,576 uint4 per array; per block 2048 sequential uint4
#pragma unroll
    for (int k = 0; k < 8; ++k) {
        int i = bid * 2048 + k * TPB + tid;
        U4H8 qa, qb;
        qa.u = magx8[i];
        qb.u = magy8[i];
#pragma unroll
        for (int j = 0; j < 4; ++j) {
            float2 va = __half22float2(qa.h[j]);
            float2 vb = __half22float2(qb.h[j]);
            s += fabsf(fmaf(va.x, ix, cx) - fmaf(vb.x, iy, cy));
            s += fabsf(fmaf(va.y, ix, cx) - fmaf(vb.y, iy, cy));
        }
    }
#pragma unroll
    for (int off = 32; off > 0; off >>= 1) s += __shfl_down(s, off, 64);
    if (lane == 0) sv[wid] = s;
    __syncthreads();
    if (tid == 0) {
        float partial = ((sv[0] + sv[1]) + (sv[2] + sv[3])) * (1.0f / (float)NVOX); // *2^-23 exact
        if (bid == 0) partial += 1e-6f;
        atomicAdd(out, partial);
    }
}

extern "C" void kernel_launch(void* const* d_in, const int* in_sizes, int n_in,
                              void* d_out, int out_size, void* d_ws, size_t ws_size,
                              hipStream_t stream) {
    const float* x = (const float*)d_in[0];
    const float* y = (const float*)d_in[1];
    // d_in[2] = kernels (weights hardcoded via separable factorization)
    float* out = (float*)d_out;

    __half* magx = (__half*)d_ws;            // NVOX halfs (16 MiB)
    __half* magy = magx + NVOX;              // NVOX halfs (16 MiB)

    pass1_kernel<<<NBLK1, 256, 0, stream>>>(x, y, magx, magy, out);
    pass2_kernel<<<GRID2, TPB, 0, stream>>>((const uint4*)magx, (const uint4*)magy, out);
}